// Round 17
// baseline (47.869 us; speedup 1.0000x reference)
//
#include <hip/hip_runtime.h>
#include <math.h>

#define TT 512
#define DD 256
#define BIGF 9999.0f
#define KK 8

typedef unsigned long long ull;
typedef __attribute__((ext_vector_type(8))) short s16x8;
typedef __attribute__((ext_vector_type(4))) float f32x4;

// ws layout (bytes)
#define HB_OFF   0            // ushort Hb[512][256]  bf16, K-swizzled, 256 KB
#define A_OFF    262144       // float  a[512]
#define B_OFF    264192       // float  b[512]
#define MB_OFF   266240       // ull    mb[512][4]    16 KB
#define MSEP_OFF 282624       // float  msep4[128]

__device__ __forceinline__ unsigned short toBf16(float f) {
  unsigned int u = __float_as_uint(f);
  unsigned int r = u + 0x7FFFu + ((u >> 16) & 1u);  // RNE
  return (unsigned short)(r >> 16);
}

// 128 blocks x 256 threads; wave w owns row 4b+w (r16-proven).
__global__ __launch_bounds__(256) void prep_kernel(
    const float* __restrict__ X, const float* __restrict__ H,
    const float* __restrict__ C, const int* __restrict__ M,
    unsigned short* __restrict__ Hb, float* __restrict__ A,
    float* __restrict__ B, ull* __restrict__ MB, float* __restrict__ MSEP4,
    float* __restrict__ out) {
  __shared__ float sm[4];
  const int b = blockIdx.x;
  const int t = threadIdx.x;
  const int wv = t >> 6, lane = t & 63;
  const int row = 4 * b + wv;
  if (b == 0 && t == 0) out[0] = 0.0f;  // re-arm accumulator every call

  const float4 h4 = *(const float4*)(H + row * DD + 4 * lane);
  const float4 x4 = *(const float4*)(X + row * DD + 4 * lane);
  const float4 c4 = *(const float4*)(C + row * DD + 4 * lane);
  const int4  m4 = *(const int4*)(M + row * DD + 4 * lane);

  // swizzled bf16 write: k0=4*lane, granule g=(k0>>3)^(row&7), koff=k0&7
  {
    ushort4 w;
    w.x = toBf16(h4.x); w.y = toBf16(h4.y);
    w.z = toBf16(h4.z); w.w = toBf16(h4.w);
    const int k0 = 4 * lane;
    const int g = (k0 >> 3) ^ (row & 7);
    *(ushort4*)(Hb + row * DD + g * 8 + (k0 & 7)) = w;
  }

  float pa = (h4.x + h4.y) + (h4.z + h4.w);
  float pb = h4.x * h4.x + h4.y * h4.y + h4.z * h4.z + h4.w * h4.w;
  const float e0 = x4.x - h4.x + c4.x;
  const float e1 = x4.y - h4.y + c4.y;
  const float e2 = x4.z - h4.z + c4.z;
  const float e3 = x4.w - h4.w + c4.w;
  float pe = (m4.x ? e0 * e0 : 0.f) + (m4.y ? e1 * e1 : 0.f) +
             (m4.z ? e2 * e2 : 0.f) + (m4.w ? e3 * e3 : 0.f);
#pragma unroll
  for (int s = 1; s < 64; s <<= 1) {
    pa += __shfl_xor(pa, s);
    pb += __shfl_xor(pb, s);
    pe += __shfl_xor(pe, s);
  }
  const ull b0 = __ballot(m4.x != 0);
  const ull b1 = __ballot(m4.y != 0);
  const ull b2 = __ballot(m4.z != 0);
  const ull b3 = __ballot(m4.w != 0);
  if (lane == 0) {
    A[row] = pa;
    B[row] = pb;
    MB[row * 4 + 0] = b0; MB[row * 4 + 1] = b1;
    MB[row * 4 + 2] = b2; MB[row * 4 + 3] = b3;
    sm[wv] = pe;
  }
  __syncthreads();
  if (t == 0) MSEP4[b] = sm[0] + sm[1] + sm[2] + sm[3];
}

// 32 blocks x 256 threads (4 waves). Block owns 16 i-rows; j swept in 8
// tiles of 64 via LDS staging (coalesced flat copies, T14 issue-early/
// write-late). A-frags r12-verbatim; epilogue mapping r13-verified
// (row = kgrp*4+r, col = frow). G stays in registers; dl/nrm in LDS
// (stride 516 -> 2-way-free banks); then proven top-8 + one atomicAdd.
__global__ __launch_bounds__(256, 1) void gramscore_kernel(
    const unsigned short* __restrict__ Hb, const float* __restrict__ A,
    const float* __restrict__ B, const ull* __restrict__ MB,
    const float* __restrict__ MSEP4, float* __restrict__ out) {
  __shared__ unsigned short At[16 * 256];  // 8 KB, swizzled
  __shared__ unsigned short Bt[64 * 256];  // 32 KB, swizzled (one j-tile)
  __shared__ float dl[16][516];            // 33 KB
  __shared__ float nrm[16][516];           // 33 KB
  __shared__ float s_rl[16];

  const int t = threadIdx.x;
  const int lane = t & 63, wv = t >> 6;
  const int bb = blockIdx.x;
  const int i0 = 16 * bb;

  // stage A-band (flat 8KB) + B tile 0 (flat 32KB), both coalesced
  {
    const s16x8* __restrict__ sa = (const s16x8*)(Hb + i0 * DD);
    s16x8* __restrict__ da = (s16x8*)At;
    da[t] = sa[t];
    da[t + 256] = sa[t + 256];
    const s16x8* __restrict__ sb = (const s16x8*)Hb;
    s16x8* __restrict__ db = (s16x8*)Bt;
#pragma unroll
    for (int q = 0; q < 8; ++q) db[q * 256 + t] = sb[q * 256 + t];
  }
  __syncthreads();

  const int frow = lane & 15;   // fragment row (A) / col (B) index
  const int kgrp = lane >> 4;   // k-group 0..3

  // A-frags: one per k-step, reused across all 8 j-tiles (r12 path)
  s16x8 afr[8];
#pragma unroll
  for (int ks = 0; ks < 8; ++ks) {
    const int g = (ks * 4 + kgrp) ^ (frow & 7);
    afr[ks] = *(const s16x8*)(At + frow * 256 + g * 8);
  }

  // per-lane i-row data (C-layout rows: li = kgrp*4 + r)
  float ai_[4], bi_[4];
  ull mi_[4][4];
#pragma unroll
  for (int r = 0; r < 4; ++r) {
    const int li = kgrp * 4 + r;
    ai_[r] = A[i0 + li];
    bi_[r] = B[i0 + li];
#pragma unroll
    for (int c = 0; c < 4; ++c) mi_[r][c] = MB[(i0 + li) * 4 + c];
  }

  s16x8 stg[8];
#pragma unroll 1
  for (int tile = 0; tile < 8; ++tile) {
    // T14: issue next tile's loads BEFORE compute (latency hides under MFMA)
    if (tile < 7) {
      const s16x8* __restrict__ sb = (const s16x8*)(Hb + (tile + 1) * 64 * DD);
#pragma unroll
      for (int q = 0; q < 8; ++q) stg[q] = sb[q * 256 + t];
    }

    // compute current tile from Bt
    const int rb = 16 * wv + frow;        // local j-row in tile
    s16x8 bfr[8];
#pragma unroll
    for (int ks = 0; ks < 8; ++ks) {
      const int g = (ks * 4 + kgrp) ^ (rb & 7);
      bfr[ks] = *(const s16x8*)(Bt + rb * 256 + g * 8);
    }
    f32x4 acc = {0.f, 0.f, 0.f, 0.f};
#pragma unroll
    for (int ks = 0; ks < 8; ++ks)
      acc = __builtin_amdgcn_mfma_f32_16x16x32_bf16(afr[ks], bfr[ks], acc,
                                                    0, 0, 0);

    // epilogue (r13-verified mapping): row li = kgrp*4+r, col jc
    const int jc = tile * 64 + rb;        // global j
    const float aj = A[jc], bj = B[jc];
    const ull mj0 = MB[jc * 4 + 0], mj1 = MB[jc * 4 + 1],
              mj2 = MB[jc * 4 + 2], mj3 = MB[jc * 4 + 3];
#pragma unroll
    for (int r = 0; r < 4; ++r) {
      const int li = kgrp * 4 + r;
      const float dot = acc[r];
      const float s2 = bi_[r] + bj - 2.0f * dot;
      const float s1 = ai_[r] - aj;
      const float var = (s2 - s1 * s1 * (1.0f / DD)) * (1.0f / (DD - 1));
      const bool diff = (mj0 != mi_[r][0]) | (mj1 != mi_[r][1]) |
                        (mj2 != mi_[r][2]) | (mj3 != mi_[r][3]);
      const bool valid = diff && (jc != i0 + li);
      dl[li][jc] = valid ? sqrtf(fmaxf(var, 0.0f)) : BIGF;
      nrm[li][jc] = sqrtf(fmaxf(s2, 0.0f));
    }
    __syncthreads();                       // all waves done reading Bt
    if (tile < 7) {
      s16x8* __restrict__ db = (s16x8*)Bt;
#pragma unroll
      for (int q = 0; q < 8; ++q) db[q * 256 + t] = stg[q];
      __syncthreads();                     // Bt ready for next tile
    }
  }

  // top-8 per row: wave wv handles local rows 4wv..4wv+3 sequentially
#pragma unroll 1
  for (int q = 0; q < 4; ++q) {
    const int w = 4 * wv + q;
    float cv[8];
#pragma unroll
    for (int c = 0; c < 8; ++c) cv[c] = dl[w][lane + 64 * c];

    float kv[KK];
    int ki[KK];
#pragma unroll
    for (int k = 0; k < KK; ++k) {
      float bv = cv[0];
      int bc = 0;
#pragma unroll
      for (int c = 1; c < 8; ++c) {
        if (cv[c] < bv) { bv = cv[c]; bc = c; }
      }
      int bidx = lane + 64 * bc;
#pragma unroll
      for (int s = 1; s < 64; s <<= 1) {
        const float ov = __shfl_xor(bv, s);
        const int oi = __shfl_xor(bidx, s);
        if (ov < bv || (ov == bv && oi < bidx)) { bv = ov; bidx = oi; }
      }
      kv[k] = bv;
      ki[k] = bidx;
      const int csel = bidx >> 6;
      const bool mine = (bidx & 63) == lane;
#pragma unroll
      for (int c = 0; c < 8; ++c) {
        if (mine && c == csel) cv[c] = BIGF;
      }
    }
    float wsum = 0.0f, rl = 0.0f;
#pragma unroll
    for (int k = 0; k < KK; ++k) {
      const float e = expf(kv[0] - kv[k]);  // kv[0] = min score
      wsum += e;
      rl += e * nrm[w][ki[k]];
    }
    if (lane == 0) s_rl[w] = rl / wsum;
  }
  __syncthreads();

  if (t == 0) {
    float v = MSEP4[4 * bb] + MSEP4[4 * bb + 1] +
              MSEP4[4 * bb + 2] + MSEP4[4 * bb + 3];
#pragma unroll
    for (int q = 0; q < 16; ++q) v += s_rl[q];
    atomicAdd(out, v);
  }
}

extern "C" void kernel_launch(void* const* d_in, const int* in_sizes, int n_in,
                              void* d_out, int out_size, void* d_ws, size_t ws_size,
                              hipStream_t stream) {
  const float* X = (const float*)d_in[0];
  const float* H = (const float*)d_in[1];
  const float* C = (const float*)d_in[2];
  const int* M = (const int*)d_in[3];
  float* out = (float*)d_out;

  char* ws = (char*)d_ws;
  unsigned short* Hb = (unsigned short*)(ws + HB_OFF);
  float* A = (float*)(ws + A_OFF);
  float* B = (float*)(ws + B_OFF);
  ull* MB = (ull*)(ws + MB_OFF);
  float* MSEP4 = (float*)(ws + MSEP_OFF);

  prep_kernel<<<128, 256, 0, stream>>>(X, H, C, M, Hb, A, B, MB, MSEP4, out);
  gramscore_kernel<<<32, 256, 0, stream>>>(Hb, A, B, MB, MSEP4, out);
}

// Round 18
// 31.602 us; speedup vs baseline: 1.5148x; 1.5148x over previous
//
#include <hip/hip_runtime.h>
#include <math.h>

#define TT 512
#define DD 256
#define BIGF 9999.0f
#define KK 8

typedef unsigned long long ull;
typedef __attribute__((ext_vector_type(8))) short s16x8;
typedef __attribute__((ext_vector_type(4))) float f32x4;

// ws layout (bytes)
#define HB_OFF   0            // ushort Hb[512][256]  bf16, K-swizzled, 256 KB
#define A_OFF    262144       // float  a[512]
#define B_OFF    264192       // float  b[512]
#define MB_OFF   266240       // ull    mb[512][4]    16 KB
#define MSEP_OFF 282624       // float  msep4[128]

__device__ __forceinline__ unsigned short toBf16(float f) {
  unsigned int u = __float_as_uint(f);
  unsigned int r = u + 0x7FFFu + ((u >> 16) & 1u);  // RNE
  return (unsigned short)(r >> 16);
}

// 128 blocks x 256 threads; wave w owns row 4b+w (r16-proven).
__global__ __launch_bounds__(256) void prep_kernel(
    const float* __restrict__ X, const float* __restrict__ H,
    const float* __restrict__ C, const int* __restrict__ M,
    unsigned short* __restrict__ Hb, float* __restrict__ A,
    float* __restrict__ B, ull* __restrict__ MB, float* __restrict__ MSEP4,
    float* __restrict__ out) {
  __shared__ float sm[4];
  const int b = blockIdx.x;
  const int t = threadIdx.x;
  const int wv = t >> 6, lane = t & 63;
  const int row = 4 * b + wv;
  if (b == 0 && t == 0) out[0] = 0.0f;  // re-arm accumulator every call

  const float4 h4 = *(const float4*)(H + row * DD + 4 * lane);
  const float4 x4 = *(const float4*)(X + row * DD + 4 * lane);
  const float4 c4 = *(const float4*)(C + row * DD + 4 * lane);
  const int4  m4 = *(const int4*)(M + row * DD + 4 * lane);

  // swizzled bf16 write: k0=4*lane, granule g=(k0>>3)^(row&7), koff=k0&7
  {
    ushort4 w;
    w.x = toBf16(h4.x); w.y = toBf16(h4.y);
    w.z = toBf16(h4.z); w.w = toBf16(h4.w);
    const int k0 = 4 * lane;
    const int g = (k0 >> 3) ^ (row & 7);
    *(ushort4*)(Hb + row * DD + g * 8 + (k0 & 7)) = w;
  }

  float pa = (h4.x + h4.y) + (h4.z + h4.w);
  float pb = h4.x * h4.x + h4.y * h4.y + h4.z * h4.z + h4.w * h4.w;
  const float e0 = x4.x - h4.x + c4.x;
  const float e1 = x4.y - h4.y + c4.y;
  const float e2 = x4.z - h4.z + c4.z;
  const float e3 = x4.w - h4.w + c4.w;
  float pe = (m4.x ? e0 * e0 : 0.f) + (m4.y ? e1 * e1 : 0.f) +
             (m4.z ? e2 * e2 : 0.f) + (m4.w ? e3 * e3 : 0.f);
#pragma unroll
  for (int s = 1; s < 64; s <<= 1) {
    pa += __shfl_xor(pa, s);
    pb += __shfl_xor(pb, s);
    pe += __shfl_xor(pe, s);
  }
  const ull b0 = __ballot(m4.x != 0);
  const ull b1 = __ballot(m4.y != 0);
  const ull b2 = __ballot(m4.z != 0);
  const ull b3 = __ballot(m4.w != 0);
  if (lane == 0) {
    A[row] = pa;
    B[row] = pb;
    MB[row * 4 + 0] = b0; MB[row * 4 + 1] = b1;
    MB[row * 4 + 2] = b2; MB[row * 4 + 3] = b3;
    sm[wv] = pe;
  }
  __syncthreads();
  if (t == 0) MSEP4[b] = sm[0] + sm[1] + sm[2] + sm[3];
}

// 256 blocks x 256 threads (4 waves), full chip. Block owns rows {2b,2b+1};
// j swept in 8 tiles of 64 (wave wv covers tile-local j 16wv..16wv+15).
// A-frag = block's 2 rows duplicated across frag rows (D-row r depends only
// on A-row r -> rows 2-15 garbage is harmless). B staged in LDS via flat
// coalesced copy + T14 issue-early/write-late. Fragment+epilogue paths are
// r17-refcheck-proven. 41 KB LDS.
__global__ __launch_bounds__(256) void gramscore_kernel(
    const unsigned short* __restrict__ Hb, const float* __restrict__ A,
    const float* __restrict__ B, const ull* __restrict__ MB,
    const float* __restrict__ MSEP4, float* __restrict__ out) {
  __shared__ unsigned short Bt[64 * 256];  // 32 KB, swizzled (one j-tile)
  __shared__ float dl[2][520];             // scores (pad vs banks)
  __shared__ float nrm[2][520];            // norms
  __shared__ float s_rl[2];

  const int t = threadIdx.x;
  const int lane = t & 63, wv = t >> 6;
  const int b = blockIdx.x;
  const int i0 = 2 * b;

  const int frow = lane & 15;   // fragment row/col index
  const int kgrp = lane >> 4;   // k-group 0..3

  // A-frags: rows i0, i0+1 duplicated across fragment rows
  const int arow = i0 + (frow & 1);
  s16x8 afr[8];
#pragma unroll
  for (int ks = 0; ks < 8; ++ks) {
    const int g = (ks * 4 + kgrp) ^ (arow & 7);
    afr[ks] = *(const s16x8*)(Hb + arow * DD + g * 8);
  }

  // uniform per-block row stats (s_load)
  const float ai0 = A[i0], ai1 = A[i0 + 1];
  const float bi0 = B[i0], bi1 = B[i0 + 1];
  const ull n00 = MB[i0 * 4 + 0], n01 = MB[i0 * 4 + 1],
            n02 = MB[i0 * 4 + 2], n03 = MB[i0 * 4 + 3];
  const ull n10 = MB[(i0 + 1) * 4 + 0], n11 = MB[(i0 + 1) * 4 + 1],
            n12 = MB[(i0 + 1) * 4 + 2], n13 = MB[(i0 + 1) * 4 + 3];

  // stage tile 0 (flat 32KB coalesced)
  {
    const s16x8* __restrict__ sb = (const s16x8*)Hb;
    s16x8* __restrict__ db = (s16x8*)Bt;
#pragma unroll
    for (int q = 0; q < 8; ++q) db[q * 256 + t] = sb[q * 256 + t];
  }
  __syncthreads();

  s16x8 stg[8];
#pragma unroll 1
  for (int tile = 0; tile < 8; ++tile) {
    // T14: issue next tile's loads BEFORE compute
    if (tile < 7) {
      const s16x8* __restrict__ sb = (const s16x8*)(Hb + (tile + 1) * 64 * DD);
#pragma unroll
      for (int q = 0; q < 8; ++q) stg[q] = sb[q * 256 + t];
    }

    // B-frags from Bt (r17 path): local j-row = 16*wv + frow
    const int rb = 16 * wv + frow;
    s16x8 bfr[8];
#pragma unroll
    for (int ks = 0; ks < 8; ++ks) {
      const int g = (ks * 4 + kgrp) ^ (rb & 7);
      bfr[ks] = *(const s16x8*)(Bt + rb * 256 + g * 8);
    }
    f32x4 acc = {0.f, 0.f, 0.f, 0.f};
#pragma unroll
    for (int ks = 0; ks < 8; ++ks)
      acc = __builtin_amdgcn_mfma_f32_16x16x32_bf16(afr[ks], bfr[ks], acc,
                                                    0, 0, 0);

    // epilogue: C-layout row = kgrp*4 + r, col = frow. Rows 0,1 live on
    // kgrp==0, regs 0,1. Col frow <-> j = tile*64 + 16*wv + frow.
    if (kgrp == 0) {
      const int jc = tile * 64 + 16 * wv + frow;
      const float aj = A[jc], bj = B[jc];
      const ull mj0 = MB[jc * 4 + 0], mj1 = MB[jc * 4 + 1],
                mj2 = MB[jc * 4 + 2], mj3 = MB[jc * 4 + 3];
      {
        const float s2 = bi0 + bj - 2.0f * acc[0];
        const float s1 = ai0 - aj;
        const float var = (s2 - s1 * s1 * (1.0f / DD)) * (1.0f / (DD - 1));
        const bool diff = (mj0 != n00) | (mj1 != n01) | (mj2 != n02) |
                          (mj3 != n03);
        const bool valid = diff && (jc != i0);
        dl[0][jc] = valid ? sqrtf(fmaxf(var, 0.0f)) : BIGF;
        nrm[0][jc] = sqrtf(fmaxf(s2, 0.0f));
      }
      {
        const float s2 = bi1 + bj - 2.0f * acc[1];
        const float s1 = ai1 - aj;
        const float var = (s2 - s1 * s1 * (1.0f / DD)) * (1.0f / (DD - 1));
        const bool diff = (mj0 != n10) | (mj1 != n11) | (mj2 != n12) |
                          (mj3 != n13);
        const bool valid = diff && (jc != i0 + 1);
        dl[1][jc] = valid ? sqrtf(fmaxf(var, 0.0f)) : BIGF;
        nrm[1][jc] = sqrtf(fmaxf(s2, 0.0f));
      }
    }
    __syncthreads();                       // all waves done reading Bt
    if (tile < 7) {
      s16x8* __restrict__ db = (s16x8*)Bt;
#pragma unroll
      for (int q = 0; q < 8; ++q) db[q * 256 + t] = stg[q];
      __syncthreads();                     // Bt ready for next tile
    }
  }

  // waves 0-1: per-row iterative top-8 smallest (lowest-index tie-break)
  if (wv < 2) {
    const int w = wv;
    float cv[8];
#pragma unroll
    for (int c = 0; c < 8; ++c) cv[c] = dl[w][lane + 64 * c];

    float kv[KK];
    int ki[KK];
#pragma unroll
    for (int k = 0; k < KK; ++k) {
      float bv = cv[0];
      int bc = 0;
#pragma unroll
      for (int c = 1; c < 8; ++c) {
        if (cv[c] < bv) { bv = cv[c]; bc = c; }
      }
      int bidx = lane + 64 * bc;
#pragma unroll
      for (int s = 1; s < 64; s <<= 1) {
        const float ov = __shfl_xor(bv, s);
        const int oi = __shfl_xor(bidx, s);
        if (ov < bv || (ov == bv && oi < bidx)) { bv = ov; bidx = oi; }
      }
      kv[k] = bv;
      ki[k] = bidx;
      const int csel = bidx >> 6;
      const bool mine = (bidx & 63) == lane;
#pragma unroll
      for (int c = 0; c < 8; ++c) {
        if (mine && c == csel) cv[c] = BIGF;
      }
    }
    float wsum = 0.0f, rl = 0.0f;
#pragma unroll
    for (int k = 0; k < KK; ++k) {
      const float e = expf(kv[0] - kv[k]);  // kv[0] = min score
      wsum += e;
      rl += e * nrm[w][ki[k]];
    }
    if (lane == 0) s_rl[w] = rl / wsum;
  }
  __syncthreads();

  if (t == 0) {
    float part = s_rl[0] + s_rl[1];
    if ((b & 1) == 0) part += MSEP4[b >> 1];
    atomicAdd(out, part);
  }
}

extern "C" void kernel_launch(void* const* d_in, const int* in_sizes, int n_in,
                              void* d_out, int out_size, void* d_ws, size_t ws_size,
                              hipStream_t stream) {
  const float* X = (const float*)d_in[0];
  const float* H = (const float*)d_in[1];
  const float* C = (const float*)d_in[2];
  const int* M = (const int*)d_in[3];
  float* out = (float*)d_out;

  char* ws = (char*)d_ws;
  unsigned short* Hb = (unsigned short*)(ws + HB_OFF);
  float* A = (float*)(ws + A_OFF);
  float* B = (float*)(ws + B_OFF);
  ull* MB = (ull*)(ws + MB_OFF);
  float* MSEP4 = (float*)(ws + MSEP_OFF);

  prep_kernel<<<128, 256, 0, stream>>>(X, H, C, M, Hb, A, B, MB, MSEP4, out);
  gramscore_kernel<<<256, 256, 0, stream>>>(Hb, A, B, MB, MSEP4, out);
}

// Round 19
// 23.119 us; speedup vs baseline: 2.0706x; 1.3669x over previous
//
#include <hip/hip_runtime.h>
#include <math.h>

#define TT 512
#define DD 256
#define BIGF 9999.0f
#define KK 8

typedef unsigned long long ull;
typedef __attribute__((ext_vector_type(8))) short s16x8;
typedef __attribute__((ext_vector_type(4))) float f32x4;

// ws layout (bytes)
#define HB_OFF   0            // ushort Hb[512][256]  bf16, K-swizzled, 256 KB
#define G_OFF    262144       // float  G[512][512]   1 MB
#define A_OFF    1310720      // float  a[512]
#define B_OFF    1312768      // float  b[512]
#define MB_OFF   1314816      // ull    mb[512][4]    16 KB
#define MSEP_OFF 1331200      // float  msep4[128]

__device__ __forceinline__ unsigned short toBf16(float f) {
  unsigned int u = __float_as_uint(f);
  unsigned int r = u + 0x7FFFu + ((u >> 16) & 1u);  // RNE
  return (unsigned short)(r >> 16);
}

__global__ __launch_bounds__(256) void prep_kernel(
    const float* __restrict__ X, const float* __restrict__ H,
    const float* __restrict__ C, const int* __restrict__ M,
    unsigned short* __restrict__ Hb, float* __restrict__ A,
    float* __restrict__ B, ull* __restrict__ MB, float* __restrict__ MSEP4,
    float* __restrict__ out) {
  const int b = blockIdx.x;
  const int t = threadIdx.x;
  const int wid = t >> 6, lane = t & 63;
  const int i0 = 4 * b;
  if (b == 0 && t == 0) out[0] = 0.0f;  // re-arm accumulator every call

  __shared__ float sA[4][4], sB[4][4], sM[4][4];
#pragma unroll
  for (int r = 0; r < 4; ++r) {
    const int row = i0 + r;
    const int idx = row * DD + t;
    const float x = X[idx], h = H[idx], c = C[idx];
    const int m = M[idx];
    // bf16 store, K-swizzled within 16B granules: dstk = t ^ ((row&7)<<3)
    const int dstk = t ^ ((row & 7) << 3);
    Hb[row * DD + dstk] = toBf16(h);
    const float e = m ? (x - h + c) : 0.0f;
    float pm = e * e, ph = h, ph2 = h * h;
#pragma unroll
    for (int s = 1; s < 64; s <<= 1) {
      pm  += __shfl_xor(pm, s);
      ph  += __shfl_xor(ph, s);
      ph2 += __shfl_xor(ph2, s);
    }
    const ull bal = __ballot(m != 0);
    if (lane == 0) {
      sA[r][wid] = ph; sB[r][wid] = ph2; sM[r][wid] = pm;
      MB[row * 4 + wid] = bal;
    }
  }
  __syncthreads();
  if (t < 4) {
    A[i0 + t] = sA[t][0] + sA[t][1] + sA[t][2] + sA[t][3];
    B[i0 + t] = sB[t][0] + sB[t][1] + sB[t][2] + sB[t][3];
  }
  if (t == 0) {
    float ms = 0.0f;
#pragma unroll
    for (int r = 0; r < 4; ++r)
#pragma unroll
      for (int wq = 0; wq < 4; ++wq) ms += sM[r][wq];
    MSEP4[b] = ms;
  }
}

// 64 blocks (8x8 tiles of 64x64), 256 threads (4 waves). K=256 fully
// LDS-resident. G = Hb . Hb^T via mfma_f32_16x16x32_bf16; symmetric, so any
// operand-transpose error is self-correcting. Swizzle (baked into Hb) makes
// fragment ds_read_b128 2-way-conflict-free.
__global__ __launch_bounds__(256, 2) void gram_kernel(
    const unsigned short* __restrict__ Hb, float* __restrict__ G) {
  __shared__ unsigned short At[64 * 256];  // 32 KB
  __shared__ unsigned short Bt[64 * 256];  // 32 KB
  const int t = threadIdx.x;
  const int lane = t & 63;
  const int wv = t >> 6;
  const int bx = blockIdx.x & 7, by = blockIdx.x >> 3;
  const int i0 = 64 * by, j0 = 64 * bx;

  // stage: flat 32KB copies (reg-staged; 16 independent loads, 1 vmcnt wait)
  {
    const s16x8* __restrict__ sa = (const s16x8*)(Hb + i0 * DD);
    const s16x8* __restrict__ sb = (const s16x8*)(Hb + j0 * DD);
    s16x8 va[8], vb[8];
#pragma unroll
    for (int q = 0; q < 8; ++q) va[q] = sa[q * 256 + t];
#pragma unroll
    for (int q = 0; q < 8; ++q) vb[q] = sb[q * 256 + t];
    s16x8* da = (s16x8*)At;
    s16x8* db = (s16x8*)Bt;
#pragma unroll
    for (int q = 0; q < 8; ++q) da[q * 256 + t] = va[q];
#pragma unroll
    for (int q = 0; q < 8; ++q) db[q * 256 + t] = vb[q];
  }
  __syncthreads();

  const int wr = wv >> 1, wc = wv & 1;  // wave quadrant (2x2 of 32x32)
  const int frow = lane & 15;
  const int kgrp = lane >> 4;           // 0..3
  const f32x4 zero = {0.f, 0.f, 0.f, 0.f};
  f32x4 acc[2][2];
  acc[0][0] = zero; acc[0][1] = zero; acc[1][0] = zero; acc[1][1] = zero;

#pragma unroll
  for (int ks = 0; ks < 8; ++ks) {
    s16x8 a[2], bfr[2];
#pragma unroll
    for (int m = 0; m < 2; ++m) {
      const int rr = 32 * wr + 16 * m + frow;
      const int g = (ks * 4 + kgrp) ^ (rr & 7);
      a[m] = *(const s16x8*)(At + rr * 256 + g * 8);
    }
#pragma unroll
    for (int n = 0; n < 2; ++n) {
      const int rr = 32 * wc + 16 * n + frow;
      const int g = (ks * 4 + kgrp) ^ (rr & 7);
      bfr[n] = *(const s16x8*)(Bt + rr * 256 + g * 8);
    }
#pragma unroll
    for (int m = 0; m < 2; ++m)
#pragma unroll
      for (int n = 0; n < 2; ++n)
        acc[m][n] = __builtin_amdgcn_mfma_f32_16x16x32_bf16(
            a[m], bfr[n], acc[m][n], 0, 0, 0);
  }

  // C/D mapping (m89-verified): col = lane&15, row = (lane>>4)*4 + reg
  const int crow0 = (lane >> 4) * 4;
  const int ccol = lane & 15;
#pragma unroll
  for (int m = 0; m < 2; ++m)
#pragma unroll
    for (int n = 0; n < 2; ++n)
#pragma unroll
      for (int r = 0; r < 4; ++r) {
        const int gr = i0 + 32 * wr + 16 * m + crow0 + r;
        const int gc = j0 + 32 * wc + 16 * n + ccol;
        G[gr * TT + gc] = acc[m][n][r];
      }
}

// 128 blocks x 256 threads. Block owns rows i0..i0+3; thread t owns
// j={2t,2t+1}. Dot comes from G (shallow float2 loads - no latency chain).
__global__ __launch_bounds__(256) void score_kernel(
    const float* __restrict__ G, const float* __restrict__ A,
    const float* __restrict__ B, const ull* __restrict__ MB,
    const float* __restrict__ MSEP4, float* __restrict__ out) {
  __shared__ float dl[4][TT];
  __shared__ float nrm[4][TT];
  __shared__ float s_rl[4];
  const int b = blockIdx.x;
  const int t = threadIdx.x;
  const int wid = t >> 6, lane = t & 63;
  const int i0 = 4 * b;

  float2 gv[4];
#pragma unroll
  for (int r = 0; r < 4; ++r)
    gv[r] = *(const float2*)(G + (i0 + r) * TT + 2 * t);

  float ai[4], bi[4];
  ull mi[4][4];
#pragma unroll
  for (int r = 0; r < 4; ++r) {
    ai[r] = A[i0 + r];
    bi[r] = B[i0 + r];
#pragma unroll
    for (int c = 0; c < 4; ++c) mi[r][c] = MB[(i0 + r) * 4 + c];
  }

#pragma unroll
  for (int jj = 0; jj < 2; ++jj) {
    const int j = 2 * t + jj;
    const float aj = A[j], bj = B[j];
    const ull m0 = MB[j * 4 + 0], m1 = MB[j * 4 + 1],
              m2 = MB[j * 4 + 2], m3 = MB[j * 4 + 3];
#pragma unroll
    for (int r = 0; r < 4; ++r) {
      const float dot = jj ? gv[r].y : gv[r].x;
      const float s2 = bi[r] + bj - 2.0f * dot;
      const float s1 = ai[r] - aj;
      const float var = (s2 - s1 * s1 * (1.0f / DD)) * (1.0f / (DD - 1));
      const bool diff = (m0 != mi[r][0]) | (m1 != mi[r][1]) |
                        (m2 != mi[r][2]) | (m3 != mi[r][3]);
      const bool valid = diff && (j != i0 + r);
      dl[r][j] = valid ? sqrtf(fmaxf(var, 0.0f)) : BIGF;
      nrm[r][j] = sqrtf(fmaxf(s2, 0.0f));
    }
  }
  __syncthreads();

  // wave w -> row i0+w: iterative top-8 smallest, lowest-index tie-break
  {
    const int w = wid;
    float cv[8];
#pragma unroll
    for (int c = 0; c < 8; ++c) cv[c] = dl[w][lane + 64 * c];

    float kv[KK];
    int ki[KK];
#pragma unroll
    for (int k = 0; k < KK; ++k) {
      float bv = cv[0];
      int bc = 0;
#pragma unroll
      for (int c = 1; c < 8; ++c) {
        if (cv[c] < bv) { bv = cv[c]; bc = c; }
      }
      int bidx = lane + 64 * bc;
#pragma unroll
      for (int s = 1; s < 64; s <<= 1) {
        const float ov = __shfl_xor(bv, s);
        const int oi = __shfl_xor(bidx, s);
        if (ov < bv || (ov == bv && oi < bidx)) { bv = ov; bidx = oi; }
      }
      kv[k] = bv;
      ki[k] = bidx;
      const int csel = bidx >> 6;
      const bool mine = (bidx & 63) == lane;
#pragma unroll
      for (int c = 0; c < 8; ++c) {
        if (mine && c == csel) cv[c] = BIGF;
      }
    }
    float wsum = 0.0f, rl = 0.0f;
#pragma unroll
    for (int k = 0; k < KK; ++k) {
      const float e = expf(kv[0] - kv[k]);  // kv[0] = min score
      wsum += e;
      rl += e * nrm[w][ki[k]];
    }
    if (lane == 0) s_rl[w] = rl / wsum;
  }
  __syncthreads();

  if (t == 0)
    atomicAdd(out, s_rl[0] + s_rl[1] + s_rl[2] + s_rl[3] + MSEP4[b]);
}

extern "C" void kernel_launch(void* const* d_in, const int* in_sizes, int n_in,
                              void* d_out, int out_size, void* d_ws, size_t ws_size,
                              hipStream_t stream) {
  const float* X = (const float*)d_in[0];
  const float* H = (const float*)d_in[1];
  const float* C = (const float*)d_in[2];
  const int* M = (const int*)d_in[3];
  float* out = (float*)d_out;

  char* ws = (char*)d_ws;
  unsigned short* Hb = (unsigned short*)(ws + HB_OFF);
  float* G = (float*)(ws + G_OFF);
  float* A = (float*)(ws + A_OFF);
  float* B = (float*)(ws + B_OFF);
  ull* MB = (ull*)(ws + MB_OFF);
  float* MSEP4 = (float*)(ws + MSEP_OFF);

  prep_kernel<<<128, 256, 0, stream>>>(X, H, C, M, Hb, A, B, MB, MSEP4, out);
  gram_kernel<<<64, 256, 0, stream>>>(Hb, G);
  score_kernel<<<128, 256, 0, stream>>>(G, A, B, MB, MSEP4, out);
}